// Round 3
// baseline (343.104 us; speedup 1.0000x reference)
//
#include <hip/hip_runtime.h>

// Edge detector stencil, reference: _get_edges with NTR=4, DTR=0.0, DELTA=3.
// Input  x: [16, 3, 512, 512] f32  -> 48 planes of 512x512.
// Output  : [16, 24, 512, 512] f32 = [48, 8, 512, 512] flat.
// 8 pixels per thread along w (two 4-px halves sharing row loads);
// float4 nontemporal stores per plane per half.

#define IMG_H 512
#define IMG_W 512

typedef float float4v __attribute__((ext_vector_type(4)));

// Core per-pixel edge logic, no boundary gating (interior use).
__device__ __forceinline__ void edge_core(
    float pcc, float pmm, float pm0, float pmp,
    float p0m, float p0p, float ppm, float pp0, float ppp,
    float p0mm, float pmm0, float pmmmm, float pppmm,
    float o[8])
{
    float d10   = pm0 - pcc;
    float dn10  = pp0 - pcc;
    float d01   = p0m - pcc;
    float dn01  = p0p - pcc;
    float d11   = pmm - pcc;
    float dnn11 = ppp - pcc;
    float dn11  = ppm - pcc;
    float d1n1  = pmp - pcc;

    float a10 = fabsf(d10),  an10  = fabsf(dn10);
    float a01 = fabsf(d01),  an01  = fabsf(dn01);
    float a11 = fabsf(d11),  ann11 = fabsf(dnn11);
    float an11 = fabsf(dn11), a1n1 = fabsf(d1n1);

    int c10 = (int)(a10 > a01) + (int)(a10 > an01) + (int)(a10 > an10)
            + 2 * (int)(a10 > fabsf(pmm - pm0))
            + (int)(a10 > fabsf(pmp - pm0));

    int c01 = (int)(a01 > a10) + (int)(a01 > an10) + (int)(a01 > an01)
            + (int)(a01 > fabsf(pmm - p0m))
            + (int)(a01 > fabsf(ppm - p0m))
            + (int)(a01 > fabsf(p0mm - p0m));

    int c11 = (int)(a11 > an11) + (int)(a11 > a1n1) + (int)(a11 > ann11)
            + (int)(a11 > fabsf(p0mm - pmm))
            + (int)(a11 > fabsf(pmm0 - pmm))
            + (int)(a11 > fabsf(pmmmm - pmm));

    int cn11 = (int)(an11 > a11) + (int)(an11 > a1n1) + (int)(an11 > ann11)
             + (int)(an11 > fabsf(p0mm - ppm))
             + 2 * (int)(an11 > fabsf(pppmm - ppm));

    o[0] = (c10 > 4 && d10 > 0.f) ? 1.f : 0.f;
    o[1] = (c10 > 4 && d10 < 0.f) ? 1.f : 0.f;
    o[2] = (c01 > 4 && d01 > 0.f) ? 1.f : 0.f;
    o[3] = (c01 > 4 && d01 < 0.f) ? 1.f : 0.f;
    o[4] = (c11 > 4 && d11 > 0.f) ? 1.f : 0.f;
    o[5] = (c11 > 4 && d11 < 0.f) ? 1.f : 0.f;
    o[6] = (cn11 > 4 && dn11 > 0.f) ? 1.f : 0.f;
    o[7] = (cn11 > 4 && dn11 < 0.f) ? 1.f : 0.f;
}

__global__ __launch_bounds__(256) void edge_kernel(const float* __restrict__ in,
                                                   float* __restrict__ out,
                                                   int nimg) {
    int idx = blockIdx.x * blockDim.x + threadIdx.x;
    int wq = idx & (IMG_W / 8 - 1);      // 0..63
    int h = (idx >> 6) & (IMG_H - 1);
    int n = idx >> 15;
    if (n >= nimg) return;
    int w0 = wq * 8;

    const float* img = in + (size_t)n * IMG_H * IMG_W;
    const size_t cs = (size_t)IMG_H * IMG_W;
    float* obase = out + ((size_t)n * 8) * cs + (size_t)h * IMG_W + w0;

    bool interior = (h >= 2) & (h <= IMG_H - 3) & (w0 >= 8) & (w0 <= IMG_W - 16);

    if (interior) {
        // Shared row spans for 8 pixels (cols relative to w0):
        const float* rowm2 = img + (h - 2) * IMG_W + w0;
        const float* rowm1 = img + (h - 1) * IMG_W + w0;
        const float* row0  = img + h * IMG_W + w0;
        const float* rowp1 = img + (h + 1) * IMG_W + w0;
        const float* rowp2 = img + (h + 2) * IMG_W + w0;

        float rm2[10], rm1[10], r0[11], rp1[10], rp2[8];
#pragma unroll
        for (int j = 0; j < 10; ++j) rm2[j] = rowm2[j - 2];  // w0-2 .. w0+7
#pragma unroll
        for (int j = 0; j < 10; ++j) rm1[j] = rowm1[j - 1];  // w0-1 .. w0+8
#pragma unroll
        for (int j = 0; j < 11; ++j) r0[j]  = row0[j - 2];   // w0-2 .. w0+8
#pragma unroll
        for (int j = 0; j < 10; ++j) rp1[j] = rowp1[j - 1];  // w0-1 .. w0+8
#pragma unroll
        for (int j = 0; j < 8; ++j)  rp2[j] = rowp2[j - 2];  // w0-2 .. w0+5

#pragma unroll
        for (int half = 0; half < 2; ++half) {
            float4v ov[8];
#pragma unroll
            for (int i4 = 0; i4 < 4; ++i4) {
                int i = half * 4 + i4;
                float o[8];
                edge_core(r0[i + 2],                      // pcc
                          rm1[i], rm1[i + 1], rm1[i + 2],
                          r0[i + 1], r0[i + 3],
                          rp1[i], rp1[i + 1], rp1[i + 2],
                          r0[i],                          // p0mm
                          rm2[i + 2],                     // pmm0
                          rm2[i],                         // pmmmm
                          rp2[i],                         // pppmm
                          o);
#pragma unroll
                for (int k = 0; k < 8; ++k) ov[k][i4] = o[k];
            }
#pragma unroll
            for (int k = 0; k < 8; ++k) {
                __builtin_nontemporal_store(
                    ov[k], (float4v*)(obase + (size_t)k * cs + half * 4));
            }
        }
    } else {
        auto ld = [&](int hh, int ww) -> float {
            bool ib = (hh >= 0) & (hh < IMG_H) & (ww >= 0) & (ww < IMG_W);
            int hc = min(max(hh, 0), IMG_H - 1);
            int wc = min(max(ww, 0), IMG_W - 1);
            float v = img[hc * IMG_W + wc];
            return ib ? v : 1.0f;
        };
        bool hge2 = h >= 2, hlt = h < IMG_H - 2;
#pragma unroll
        for (int half = 0; half < 2; ++half) {
            float4v ov[8];
#pragma unroll
            for (int i4 = 0; i4 < 4; ++i4) {
                int w = w0 + half * 4 + i4;
                float o[8];
                edge_core(ld(h, w),
                          ld(h - 1, w - 1), ld(h - 1, w), ld(h - 1, w + 1),
                          ld(h, w - 1), ld(h, w + 1),
                          ld(h + 1, w - 1), ld(h + 1, w), ld(h + 1, w + 1),
                          ld(h, w - 2),
                          ld(h - 2, w),
                          ld(h - 2, w - 2),
                          ld(h + 2, w - 2),
                          o);
                bool wge2 = w >= 2, wlt = w < IMG_W - 2;
                ov[0][i4] = (hge2)         ? o[0] : 0.f;
                ov[1][i4] = (hlt)          ? o[1] : 0.f;
                ov[2][i4] = (wge2)         ? o[2] : 0.f;
                ov[3][i4] = (wlt)          ? o[3] : 0.f;
                ov[4][i4] = (hge2 && wge2) ? o[4] : 0.f;
                ov[5][i4] = (hlt && wlt)   ? o[5] : 0.f;
                ov[6][i4] = (hlt && wge2)  ? o[6] : 0.f;
                ov[7][i4] = (hge2 && wlt)  ? o[7] : 0.f;
            }
#pragma unroll
            for (int k = 0; k < 8; ++k) {
                __builtin_nontemporal_store(
                    ov[k], (float4v*)(obase + (size_t)k * cs + half * 4));
            }
        }
    }
}

extern "C" void kernel_launch(void* const* d_in, const int* in_sizes, int n_in,
                              void* d_out, int out_size, void* d_ws, size_t ws_size,
                              hipStream_t stream) {
    const float* x = (const float*)d_in[0];
    float* out = (float*)d_out;
    int nimg = in_sizes[0] / (IMG_H * IMG_W);                 // 48
    long long total = (long long)nimg * IMG_H * (IMG_W / 8);  // threads
    int block = 256;
    int grid = (int)((total + block - 1) / block);
    edge_kernel<<<grid, block, 0, stream>>>(x, out, nimg);
}

// Round 4
// 115.215 us; speedup vs baseline: 2.9779x; 2.9779x over previous
//
#include <hip/hip_runtime.h>

// Edge detector stencil, reference: _get_edges with NTR=4, DTR=0.0, DELTA=3.
// Input  x: [16, 3, 512, 512] f32  -> 48 planes of 512x512.
// Output  : [16, 24, 512, 512] f32 = [48, 8, 512, 512] flat.
//
// Layout: 4 px/thread along w, 2 rows/thread (shares 6 row-spans of loads).
// Stores: float4 nontemporal, DENSE per instruction (lane i -> i*16B within
// the wave) — round 3 showed strided NT stores cost exactly 2x HBM write
// amplification (WRITE_SIZE 789k KB vs 393k ideal).
// XCD-contiguous block swizzle so adjacent row-stripes share halo rows in
// the same XCD's L2 (grid 6144 divisible by 8; bijective).

#define IMG_H 512
#define IMG_W 512

typedef float float4v __attribute__((ext_vector_type(4)));

__device__ __forceinline__ void edge_core(
    float pcc, float pmm, float pm0, float pmp,
    float p0m, float p0p, float ppm, float pp0, float ppp,
    float p0mm, float pmm0, float pmmmm, float pppmm,
    float o[8])
{
    float d10   = pm0 - pcc;
    float dn10  = pp0 - pcc;
    float d01   = p0m - pcc;
    float dn01  = p0p - pcc;
    float d11   = pmm - pcc;
    float dnn11 = ppp - pcc;
    float dn11  = ppm - pcc;
    float d1n1  = pmp - pcc;

    float a10 = fabsf(d10),  an10  = fabsf(dn10);
    float a01 = fabsf(d01),  an01  = fabsf(dn01);
    float a11 = fabsf(d11),  ann11 = fabsf(dnn11);
    float an11 = fabsf(dn11), a1n1 = fabsf(d1n1);

    int c10 = (int)(a10 > a01) + (int)(a10 > an01) + (int)(a10 > an10)
            + 2 * (int)(a10 > fabsf(pmm - pm0))
            + (int)(a10 > fabsf(pmp - pm0));

    int c01 = (int)(a01 > a10) + (int)(a01 > an10) + (int)(a01 > an01)
            + (int)(a01 > fabsf(pmm - p0m))
            + (int)(a01 > fabsf(ppm - p0m))
            + (int)(a01 > fabsf(p0mm - p0m));

    int c11 = (int)(a11 > an11) + (int)(a11 > a1n1) + (int)(a11 > ann11)
            + (int)(a11 > fabsf(p0mm - pmm))
            + (int)(a11 > fabsf(pmm0 - pmm))
            + (int)(a11 > fabsf(pmmmm - pmm));

    int cn11 = (int)(an11 > a11) + (int)(an11 > a1n1) + (int)(an11 > ann11)
             + (int)(an11 > fabsf(p0mm - ppm))
             + 2 * (int)(an11 > fabsf(pppmm - ppm));

    o[0] = (c10 > 4 && d10 > 0.f) ? 1.f : 0.f;
    o[1] = (c10 > 4 && d10 < 0.f) ? 1.f : 0.f;
    o[2] = (c01 > 4 && d01 > 0.f) ? 1.f : 0.f;
    o[3] = (c01 > 4 && d01 < 0.f) ? 1.f : 0.f;
    o[4] = (c11 > 4 && d11 > 0.f) ? 1.f : 0.f;
    o[5] = (c11 > 4 && d11 < 0.f) ? 1.f : 0.f;
    o[6] = (cn11 > 4 && dn11 > 0.f) ? 1.f : 0.f;
    o[7] = (cn11 > 4 && dn11 < 0.f) ? 1.f : 0.f;
}

__global__ __launch_bounds__(256) void edge_kernel(const float* __restrict__ in,
                                                   float* __restrict__ out,
                                                   int nimg) {
    // XCD-contiguous bijective swizzle: 8 XCDs, grid % 8 == 0.
    int bid = blockIdx.x;
    int cpx = gridDim.x >> 3;                 // blocks per XCD chunk
    int swz = (bid & 7) * cpx + (bid >> 3);
    int idx = swz * 256 + threadIdx.x;

    int wq = idx & (IMG_W / 4 - 1);           // 0..127 (4-px column group)
    int hp = (idx >> 7) & (IMG_H / 2 - 1);    // 0..255 (row pair)
    int n  = idx >> 15;                       // image plane
    if (n >= nimg) return;
    int w0 = wq * 4;
    int h0 = hp * 2;

    const float* img = in + (size_t)n * IMG_H * IMG_W;
    const size_t cs = (size_t)IMG_H * IMG_W;
    float* obase = out + ((size_t)n * 8) * cs + (size_t)h0 * IMG_W + w0;

    bool interior = (h0 >= 2) & (h0 <= IMG_H - 4) & (w0 >= 4) & (w0 <= IMG_W - 8);

    if (interior) {
        // Six row spans rows h0-2 .. h0+3 (cols relative to w0-2 base):
        const float* rA = img + (h0 - 2) * IMG_W + w0 - 2;
        const float* rB = img + (h0 - 1) * IMG_W + w0 - 2;
        const float* rC = img + (h0    ) * IMG_W + w0 - 2;
        const float* rD = img + (h0 + 1) * IMG_W + w0 - 2;
        const float* rE = img + (h0 + 2) * IMG_W + w0 - 2;
        const float* rF = img + (h0 + 3) * IMG_W + w0 - 2;

        float a[6], b[7], c[7], d[7], e[7], f[4];
#pragma unroll
        for (int j = 0; j < 6; ++j) a[j] = rA[j];   // w0-2 .. w0+3
#pragma unroll
        for (int j = 0; j < 7; ++j) b[j] = rB[j];   // w0-2 .. w0+4
#pragma unroll
        for (int j = 0; j < 7; ++j) c[j] = rC[j];
#pragma unroll
        for (int j = 0; j < 7; ++j) d[j] = rD[j];
#pragma unroll
        for (int j = 0; j < 7; ++j) e[j] = rE[j];
#pragma unroll
        for (int j = 0; j < 4; ++j) f[j] = rF[j];   // w0-2 .. w0+1

        // ---- output row h0 (rm2=a, rm1=b, r0=c, rp1=d, rp2=e) ----
        {
            float4v ov[8];
#pragma unroll
            for (int i = 0; i < 4; ++i) {
                float o[8];
                edge_core(c[i + 2],
                          b[i + 1], b[i + 2], b[i + 3],
                          c[i + 1], c[i + 3],
                          d[i + 1], d[i + 2], d[i + 3],
                          c[i],            // p0mm  (h, w-2)
                          a[i + 2],        // pmm0  (h-2, w)
                          a[i],            // pmmmm (h-2, w-2)
                          e[i],            // pppmm (h+2, w-2)
                          o);
#pragma unroll
                for (int k = 0; k < 8; ++k) ov[k][i] = o[k];
            }
#pragma unroll
            for (int k = 0; k < 8; ++k)
                __builtin_nontemporal_store(ov[k], (float4v*)(obase + (size_t)k * cs));
        }
        // ---- output row h0+1 (rm2=b, rm1=c, r0=d, rp1=e, rp2=f) ----
        {
            float4v ov[8];
#pragma unroll
            for (int i = 0; i < 4; ++i) {
                float o[8];
                edge_core(d[i + 2],
                          c[i + 1], c[i + 2], c[i + 3],
                          d[i + 1], d[i + 3],
                          e[i + 1], e[i + 2], e[i + 3],
                          d[i],            // p0mm
                          b[i + 2],        // pmm0  (h-1 of row h0+1 is rB+1 = rC? no: h0+1-2 = h0-1 = rB)
                          b[i],            // pmmmm
                          f[i],            // pppmm (h0+3, w-2)
                          o);
#pragma unroll
                for (int k = 0; k < 8; ++k) ov[k][i] = o[k];
            }
#pragma unroll
            for (int k = 0; k < 8; ++k)
                __builtin_nontemporal_store(ov[k], (float4v*)(obase + (size_t)k * cs + IMG_W));
        }
    } else {
        auto ld = [&](int hh, int ww) -> float {
            bool ib = (hh >= 0) & (hh < IMG_H) & (ww >= 0) & (ww < IMG_W);
            int hc = min(max(hh, 0), IMG_H - 1);
            int wc = min(max(ww, 0), IMG_W - 1);
            float v = img[hc * IMG_W + wc];
            return ib ? v : 1.0f;
        };
#pragma unroll
        for (int r = 0; r < 2; ++r) {
            int h = h0 + r;
            bool hge2 = h >= 2, hlt = h < IMG_H - 2;
            float4v ov[8];
#pragma unroll
            for (int i = 0; i < 4; ++i) {
                int w = w0 + i;
                float o[8];
                edge_core(ld(h, w),
                          ld(h - 1, w - 1), ld(h - 1, w), ld(h - 1, w + 1),
                          ld(h, w - 1), ld(h, w + 1),
                          ld(h + 1, w - 1), ld(h + 1, w), ld(h + 1, w + 1),
                          ld(h, w - 2),
                          ld(h - 2, w),
                          ld(h - 2, w - 2),
                          ld(h + 2, w - 2),
                          o);
                bool wge2 = w >= 2, wlt = w < IMG_W - 2;
                ov[0][i] = (hge2)         ? o[0] : 0.f;
                ov[1][i] = (hlt)          ? o[1] : 0.f;
                ov[2][i] = (wge2)         ? o[2] : 0.f;
                ov[3][i] = (wlt)          ? o[3] : 0.f;
                ov[4][i] = (hge2 && wge2) ? o[4] : 0.f;
                ov[5][i] = (hlt && wlt)   ? o[5] : 0.f;
                ov[6][i] = (hlt && wge2)  ? o[6] : 0.f;
                ov[7][i] = (hge2 && wlt)  ? o[7] : 0.f;
            }
#pragma unroll
            for (int k = 0; k < 8; ++k)
                __builtin_nontemporal_store(
                    ov[k], (float4v*)(obase + (size_t)k * cs + r * IMG_W));
        }
    }
}

extern "C" void kernel_launch(void* const* d_in, const int* in_sizes, int n_in,
                              void* d_out, int out_size, void* d_ws, size_t ws_size,
                              hipStream_t stream) {
    const float* x = (const float*)d_in[0];
    float* out = (float*)d_out;
    int nimg = in_sizes[0] / (IMG_H * IMG_W);                 // 48
    long long total = (long long)nimg * (IMG_H / 2) * (IMG_W / 4);  // threads
    int block = 256;
    int grid = (int)((total + block - 1) / block);            // 6144, % 8 == 0
    edge_kernel<<<grid, block, 0, stream>>>(x, out, nimg);
}